// Round 2
// baseline (224.686 us; speedup 1.0000x reference)
//
#include <hip/hip_runtime.h>
#include <hip/hip_bf16.h>

#define B_ 2
#define N_ 512
#define D_ 64
#define H_ 128
#define OUT_ 64

using bf16x8 = __attribute__((ext_vector_type(8))) __bf16;
using f32x4  = __attribute__((ext_vector_type(4))) float;
using f32x8  = __attribute__((ext_vector_type(8))) float;

// ws layout (bytes):
//   xa_b1 : float[B*N*H]          @ 0        (524288)
//   xb    : float[B*N*H]          @ 524288   (524288)
//   w2t   : bf16 [H*H]            @ 1048576  (32768)
//   S     : float[B*H]            @ 1081344  (1024)

// grid 512 blocks x 256 thr. Block handles 2 tokens x 128 h, plus a 32-elem
// strip of the W2^T bf16 conversion; block 0 zeroes S.
__global__ __launch_bounds__(256) void prep_kernel(
    const float* __restrict__ x, const float* __restrict__ W1,
    const float* __restrict__ b1, const float* __restrict__ W2,
    float* __restrict__ xa, float* __restrict__ xb,
    __hip_bfloat16* __restrict__ w2t, float* __restrict__ S)
{
    const int tid = threadIdx.x;
    const int blk = blockIdx.x;
    __shared__ float xs[128];            // 2 tokens x 64 features
    if (tid < 128) xs[tid] = x[blk * 128 + tid];
    if (tid < 32) {                      // W2^T strip: 512 blocks x 32 = 16384
        int e = blk * 32 + tid;
        int k = e & (H_ - 1), n = e >> 7;
        w2t[n * H_ + k] = __float2bfloat16(W2[k * H_ + n]);
    }
    if (blk == 0) S[tid] = 0.f;          // B_*H_ = 256 = blockDim
    __syncthreads();

    const int h = tid & (H_ - 1);
    const int which = tid >> 7;          // token 0/1 within block
    const float* xr = xs + which * D_;
    const float* Wa = W1 + h;
    const float* Wb = W1 + D_ * H_ + h;
    float a0 = 0.f, a1 = 0.f, p0 = 0.f, p1 = 0.f;
    #pragma unroll 8
    for (int k = 0; k < D_; k += 2) {
        float x0 = xr[k], x1 = xr[k + 1];
        a0 += x0 * Wa[k * H_];
        a1 += x1 * Wa[(k + 1) * H_];
        p0 += x0 * Wb[k * H_];
        p1 += x1 * Wb[(k + 1) * H_];
    }
    const int bn = blk * 2 + which;
    xa[bn * H_ + h] = a0 + a1 + b1[h];   // fold b1 into xa
    xb[bn * H_ + h] = p0 + p1;
}

// Block: 256 threads (4 waves). Tile: 32 i x 16 j; wave w handles i's
// [i0+8w, i0+8w+8), r-loop fully unrolled so loads pipeline.
// W2^T fragments live in VGPRs for the whole block.
__global__ __launch_bounds__(256, 2) void pair_kernel(
    const float* __restrict__ xa, const float* __restrict__ xb,
    const uint4* __restrict__ w2t, const float* __restrict__ b2,
    float* __restrict__ S)
{
    const int tid  = threadIdx.x;
    const int lane = tid & 63;
    const int wid  = tid >> 6;
    const int l15  = lane & 15;
    const int quad = lane >> 4;

    const int j0 = blockIdx.x * 16;
    const int i0 = blockIdx.y * 32;
    const int b  = blockIdx.z;

    // B fragments: bfrag[c][s] = W2^T[16c+l15][32s + 8*quad .. +8]
    bf16x8 bfrag[8][4];
    #pragma unroll
    for (int c = 0; c < 8; c++) {
        int row = 16 * c + l15;
        #pragma unroll
        for (int s = 0; s < 4; s++) {
            union { uint4 u; bf16x8 v; } cv;
            cv.u = w2t[row * 16 + s * 4 + quad];
            bfrag[c][s] = cv.v;
        }
    }

    // xa(+b1) for this block's 16 j's: lane holds k = 32s + 8*quad + t
    const float* xaB = xa + (size_t)(b * N_ + j0 + l15) * H_ + quad * 8;
    f32x8 av[4];
    #pragma unroll
    for (int s = 0; s < 4; s++) av[s] = *(const f32x8*)(xaB + s * 32);

    float b2s[8];
    #pragma unroll
    for (int c = 0; c < 8; c++) b2s[c] = b2[16 * c + l15];

    f32x4 csum[8];
    #pragma unroll
    for (int c = 0; c < 8; c++) csum[c] = (f32x4)0.f;

    const float* xbB = xb + (size_t)(b * N_ + i0 + wid * 8) * H_ + quad * 8;

    #pragma unroll
    for (int r = 0; r < 8; r++) {
        const float* xr = xbB + r * H_;
        // A fragments: relu(xa[j0+l15] + xb[i]) -> bf16, packed ops
        bf16x8 afr[4];
        #pragma unroll
        for (int s = 0; s < 4; s++) {
            f32x8 u = *(const f32x8*)(xr + s * 32);
            f32x8 v = av[s] + u;
            v = __builtin_elementwise_max(v, (f32x8)0.f);
            afr[s] = __builtin_convertvector(v, bf16x8);
        }
        #pragma unroll
        for (int c = 0; c < 8; c++) {
            f32x4 acc = (f32x4)0.f;
            #pragma unroll
            for (int s = 0; s < 4; s++)
                acc = __builtin_amdgcn_mfma_f32_16x16x32_bf16(afr[s], bfrag[c][s], acc, 0, 0, 0);
            f32x4 t = acc + b2s[c];                       // +bias (splat)
            t = __builtin_elementwise_max(t, (f32x4)0.f); // relu
            csum[c] += t;                                 // row-accumulate
        }
    }

    // Lane now has 4 partial row-sums per column 16c+l15; reduce regs + quads.
    __shared__ float sred[4][H_];
    #pragma unroll
    for (int c = 0; c < 8; c++) {
        float v = (csum[c][0] + csum[c][1]) + (csum[c][2] + csum[c][3]);
        v += __shfl_xor(v, 16, 64);
        v += __shfl_xor(v, 32, 64);
        if (quad == 0) sred[wid][c * 16 + l15] = v;
    }
    __syncthreads();
    if (tid < H_) {
        float tot = sred[0][tid] + sred[1][tid] + sred[2][tid] + sred[3][tid];
        atomicAdd(&S[b * H_ + tid], tot);
    }
}

__global__ __launch_bounds__(128) void tail_kernel(
    const float* __restrict__ S, const float* __restrict__ W3,
    const float* __restrict__ b3, const float* __restrict__ V1,
    const float* __restrict__ c1, const float* __restrict__ V2,
    const float* __restrict__ c2, float* __restrict__ out)
{
    __shared__ float pool[H_], ov[H_];
    const int b = blockIdx.x, t = threadIdx.x;
    const float* Sb = S + b * H_;
    float acc = 0.f;
    #pragma unroll 8
    for (int k = 0; k < H_; k++) acc += Sb[k] * W3[k * H_ + t];
    pool[t] = acc + (float)(N_ * N_) * b3[t];
    __syncthreads();
    acc = c1[t];
    #pragma unroll 8
    for (int k = 0; k < H_; k++) acc += pool[k] * V1[k * H_ + t];
    ov[t] = acc > 0.f ? acc : 0.f;
    __syncthreads();
    if (t < OUT_) {
        acc = c2[t];
        #pragma unroll 8
        for (int k = 0; k < H_; k++) acc += ov[k] * V2[k * OUT_ + t];
        out[b * OUT_ + t] = acc;
    }
}

extern "C" void kernel_launch(void* const* d_in, const int* in_sizes, int n_in,
                              void* d_out, int out_size, void* d_ws, size_t ws_size,
                              hipStream_t stream) {
    const float* x  = (const float*)d_in[0];
    const float* W1 = (const float*)d_in[1];
    const float* b1 = (const float*)d_in[2];
    const float* W2 = (const float*)d_in[3];
    const float* b2 = (const float*)d_in[4];
    const float* W3 = (const float*)d_in[5];
    const float* b3 = (const float*)d_in[6];
    const float* V1 = (const float*)d_in[7];
    const float* c1 = (const float*)d_in[8];
    const float* V2 = (const float*)d_in[9];
    const float* c2 = (const float*)d_in[10];
    float* out = (float*)d_out;

    char* ws = (char*)d_ws;
    float*          xa  = (float*)(ws);
    float*          xb  = (float*)(ws + 524288);
    __hip_bfloat16* w2t = (__hip_bfloat16*)(ws + 1048576);
    float*          S   = (float*)(ws + 1048576 + 32768);

    prep_kernel<<<B_ * N_ / 2, 256, 0, stream>>>(x, W1, b1, W2, xa, xb, w2t, S);
    dim3 g2(N_ / 16, N_ / 32, B_);
    pair_kernel<<<g2, 256, 0, stream>>>(xa, xb, (const uint4*)w2t, b2, S);
    tail_kernel<<<B_, 128, 0, stream>>>(S, W3, b3, V1, c1, V2, c2, out);
}

// Round 3
// 202.313 us; speedup vs baseline: 1.1106x; 1.1106x over previous
//
#include <hip/hip_runtime.h>
#include <hip/hip_bf16.h>

#define B_ 2
#define N_ 512
#define D_ 64
#define H_ 128
#define OUT_ 64
#define GRID2 ((N_ / 16) * (N_ / 32) * B_)   // 1024 pair blocks

using bf16x8 = __attribute__((ext_vector_type(8))) __bf16;
using f32x4  = __attribute__((ext_vector_type(4))) float;
using f32x8  = __attribute__((ext_vector_type(8))) float;

// ws layout (bytes):
//   xa_b1 : float[B*N*H]          @ 0        (524288)
//   xb    : float[B*N*H]          @ 524288   (524288)
//   w2t   : bf16 [H*H]            @ 1048576  (32768)
//   S     : float[B*H]            @ 1081344  (1024)
//   cnt   : int                   @ 1082368  (4)

__global__ __launch_bounds__(256) void prep_kernel(
    const float* __restrict__ x, const float* __restrict__ W1,
    const float* __restrict__ b1, const float* __restrict__ W2,
    float* __restrict__ xa, float* __restrict__ xb,
    __hip_bfloat16* __restrict__ w2t, float* __restrict__ S,
    int* __restrict__ counter)
{
    int idx = blockIdx.x * 256 + threadIdx.x;
    if (idx < B_ * N_ * H_) {
        int h  = idx & (H_ - 1);
        int bn = idx >> 7;                 // b*N + n
        const float* xr = x + bn * D_;
        float aa = 0.f, ab = 0.f;
        #pragma unroll
        for (int k = 0; k < D_; k++) {
            float xv = xr[k];
            aa += xv * W1[k * H_ + h];
            ab += xv * W1[(k + D_) * H_ + h];
        }
        xa[idx] = aa + b1[h];              // fold b1 into xa
        xb[idx] = ab;
    }
    if (idx < H_ * H_) {                   // W2 transposed, bf16
        int k = idx & (H_ - 1);
        int n = idx >> 7;
        w2t[n * H_ + k] = __float2bfloat16(W2[k * H_ + n]);
    }
    if (idx < B_ * H_) S[idx] = 0.f;
    if (idx == 0) *counter = 0;
}

// Block: 256 threads (4 waves). Tile: 32 i x 16 j; wave w handles i's
// [i0+8w, i0+8w+8). W2^T fragments live in VGPRs for the whole block.
// Last block to finish folds in the tail MLP (S@W3 -> relu(@V1) -> @V2).
__global__ __launch_bounds__(256, 2) void pair_kernel(
    const float* __restrict__ xa, const float* __restrict__ xb,
    const uint4* __restrict__ w2t, const float* __restrict__ b2,
    float* __restrict__ S, int* __restrict__ counter,
    const float* __restrict__ W3, const float* __restrict__ b3,
    const float* __restrict__ V1, const float* __restrict__ c1,
    const float* __restrict__ V2, const float* __restrict__ c2,
    float* __restrict__ out)
{
    const int tid  = threadIdx.x;
    const int lane = tid & 63;
    const int wid  = tid >> 6;
    const int l15  = lane & 15;
    const int quad = lane >> 4;

    const int j0 = blockIdx.x * 16;
    const int i0 = blockIdx.y * 32;
    const int b  = blockIdx.z;

    // B fragments: bfrag[c][s] = W2^T[16c+l15][32s + 8*quad .. +8]
    bf16x8 bfrag[8][4];
    #pragma unroll
    for (int c = 0; c < 8; c++) {
        int row = 16 * c + l15;
        #pragma unroll
        for (int s = 0; s < 4; s++) {
            union { uint4 u; bf16x8 v; } cv;
            cv.u = w2t[row * 16 + s * 4 + quad];
            bfrag[c][s] = cv.v;
        }
    }

    // xa(+b1) for this block's 16 j's: lane holds k = 32s + 8*quad + t
    const float* xaB = xa + (size_t)(b * N_ + j0 + l15) * H_ + quad * 8;
    f32x8 av[4];
    #pragma unroll
    for (int s = 0; s < 4; s++) av[s] = *(const f32x8*)(xaB + s * 32);

    float b2s[8];
    #pragma unroll
    for (int c = 0; c < 8; c++) b2s[c] = b2[16 * c + l15];

    f32x4 csum[8];
    #pragma unroll
    for (int c = 0; c < 8; c++) csum[c] = (f32x4)0.f;

    const float* xbB = xb + (size_t)(b * N_ + i0 + wid * 8) * H_ + quad * 8;

    #pragma unroll 2
    for (int r = 0; r < 8; r++) {
        const float* xr = xbB + r * H_;
        // A fragments: relu(xa[j] + xb[i]) -> bf16, packed ops
        bf16x8 afr[4];
        #pragma unroll
        for (int s = 0; s < 4; s++) {
            f32x8 u = *(const f32x8*)(xr + s * 32);
            f32x8 v = av[s] + u;
            v = __builtin_elementwise_max(v, (f32x8)0.f);
            afr[s] = __builtin_convertvector(v, bf16x8);
        }
        #pragma unroll
        for (int c = 0; c < 8; c++) {
            f32x4 acc = (f32x4)0.f;
            #pragma unroll
            for (int s = 0; s < 4; s++)
                acc = __builtin_amdgcn_mfma_f32_16x16x32_bf16(afr[s], bfrag[c][s], acc, 0, 0, 0);
            f32x4 t = acc + b2s[c];                       // +bias (splat)
            t = __builtin_elementwise_max(t, (f32x4)0.f); // relu
            csum[c] += t;                                 // row-accumulate
        }
    }

    // Reduce 4 acc-rows per lane, then quads, then waves via LDS.
    __shared__ float sred[4][H_];
    #pragma unroll
    for (int c = 0; c < 8; c++) {
        float v = (csum[c][0] + csum[c][1]) + (csum[c][2] + csum[c][3]);
        v += __shfl_xor(v, 16, 64);
        v += __shfl_xor(v, 32, 64);
        if (quad == 0) sred[wid][c * 16 + l15] = v;
    }
    __syncthreads();
    if (tid < H_) {
        float tot = sred[0][tid] + sred[1][tid] + sred[2][tid] + sred[3][tid];
        atomicAdd(&S[b * H_ + tid], tot);
    }

    // ---- last-block tail ----
    __shared__ int sticket;
    __threadfence();                       // make S atomics visible first
    __syncthreads();
    if (tid == 0) sticket = atomicAdd(counter, 1);
    __syncthreads();
    if (sticket == GRID2 - 1) {
        __threadfence();                   // acquire: see all blocks' S adds
        __shared__ float pool[H_], ov[H_];
        for (int bb = 0; bb < B_; bb++) {
            const float* Sb = S + bb * H_;
            if (tid < H_) {
                float acc = 0.f;
                #pragma unroll 8
                for (int k = 0; k < H_; k++) acc += Sb[k] * W3[k * H_ + tid];
                pool[tid] = acc + (float)(N_ * N_) * b3[tid];
            }
            __syncthreads();
            if (tid < H_) {
                float acc = c1[tid];
                #pragma unroll 8
                for (int k = 0; k < H_; k++) acc += pool[k] * V1[k * H_ + tid];
                ov[tid] = acc > 0.f ? acc : 0.f;
            }
            __syncthreads();
            if (tid < OUT_) {
                float acc = c2[tid];
                #pragma unroll 8
                for (int k = 0; k < H_; k++) acc += ov[k] * V2[k * OUT_ + tid];
                out[bb * OUT_ + tid] = acc;
            }
            __syncthreads();
        }
    }
}

extern "C" void kernel_launch(void* const* d_in, const int* in_sizes, int n_in,
                              void* d_out, int out_size, void* d_ws, size_t ws_size,
                              hipStream_t stream) {
    const float* x  = (const float*)d_in[0];
    const float* W1 = (const float*)d_in[1];
    const float* b1 = (const float*)d_in[2];
    const float* W2 = (const float*)d_in[3];
    const float* b2 = (const float*)d_in[4];
    const float* W3 = (const float*)d_in[5];
    const float* b3 = (const float*)d_in[6];
    const float* V1 = (const float*)d_in[7];
    const float* c1 = (const float*)d_in[8];
    const float* V2 = (const float*)d_in[9];
    const float* c2 = (const float*)d_in[10];
    float* out = (float*)d_out;

    char* ws = (char*)d_ws;
    float*          xa  = (float*)(ws);
    float*          xb  = (float*)(ws + 524288);
    __hip_bfloat16* w2t = (__hip_bfloat16*)(ws + 1048576);
    float*          S   = (float*)(ws + 1048576 + 32768);
    int*            cnt = (int*)(ws + 1048576 + 32768 + 1024);

    prep_kernel<<<512, 256, 0, stream>>>(x, W1, b1, W2, xa, xb, w2t, S, cnt);
    dim3 g2(N_ / 16, N_ / 32, B_);
    pair_kernel<<<g2, 256, 0, stream>>>(xa, xb, (const uint4*)w2t, b2, S, cnt,
                                        W3, b3, V1, c1, V2, c2, out);
}

// Round 4
// 148.705 us; speedup vs baseline: 1.5110x; 1.3605x over previous
//
#include <hip/hip_runtime.h>
#include <hip/hip_bf16.h>

#define B_ 2
#define N_ 512
#define D_ 64
#define H_ 128
#define OUT_ 64

using bf16x8 = __attribute__((ext_vector_type(8))) __bf16;
using f32x4  = __attribute__((ext_vector_type(4))) float;
using f32x8  = __attribute__((ext_vector_type(8))) float;

// ws layout (bytes):
//   xa_b1 : float[B*N*H]          @ 0        (524288)
//   xb    : float[B*N*H]          @ 524288   (524288)
//   w2t   : bf16 [H*H]            @ 1048576  (32768)
//   S     : float[B*H]            @ 1081344  (1024)

// One block per token (1024 blocks). Thread t: half = t>>7 selects xa/xb,
// h = t&127 the output feature. 64 independent coalesced MACs.
__global__ __launch_bounds__(256) void prep_kernel(
    const float* __restrict__ x, const float* __restrict__ W1,
    const float* __restrict__ b1, const float* __restrict__ W2,
    float* __restrict__ xa, float* __restrict__ xb,
    __hip_bfloat16* __restrict__ w2t, float* __restrict__ S)
{
    const int bn  = blockIdx.x;            // b*N + n
    const int tid = threadIdx.x;
    __shared__ float xs[D_];
    if (tid < D_) xs[tid] = x[bn * D_ + tid];
    if (bn < 64) {                          // W2^T bf16: 64 blocks x 256
        int e = bn * 256 + tid;
        int k = e & (H_ - 1), n = e >> 7;
        w2t[n * H_ + k] = __float2bfloat16(W2[k * H_ + n]);
    }
    if (bn == 64) S[tid] = 0.f;             // B_*H_ = 256
    __syncthreads();

    const int h    = tid & (H_ - 1);
    const int half = tid >> 7;              // 0 -> xa (W1 rows 0..63), 1 -> xb
    const float* Wcol = W1 + half * D_ * H_ + h;
    float acc = 0.f;
    #pragma unroll
    for (int k = 0; k < D_; k++) acc += xs[k] * Wcol[k * H_];
    if (half == 0) xa[bn * H_ + h] = acc + b1[h];
    else           xb[bn * H_ + h] = acc;
}

// Block: 256 threads (4 waves). Tile: 32 i x 16 j; wave w handles i's
// [i0+8w, i0+8w+8). W2^T fragments live in VGPRs for the whole block.
__global__ __launch_bounds__(256, 2) void pair_kernel(
    const float* __restrict__ xa, const float* __restrict__ xb,
    const uint4* __restrict__ w2t, const float* __restrict__ b2,
    float* __restrict__ S)
{
    const int tid  = threadIdx.x;
    const int lane = tid & 63;
    const int wid  = tid >> 6;
    const int l15  = lane & 15;
    const int quad = lane >> 4;

    const int j0 = blockIdx.x * 16;
    const int i0 = blockIdx.y * 32;
    const int b  = blockIdx.z;

    // B fragments: bfrag[c][s] = W2^T[16c+l15][32s + 8*quad .. +8]
    bf16x8 bfrag[8][4];
    #pragma unroll
    for (int c = 0; c < 8; c++) {
        int row = 16 * c + l15;
        #pragma unroll
        for (int s = 0; s < 4; s++) {
            union { uint4 u; bf16x8 v; } cv;
            cv.u = w2t[row * 16 + s * 4 + quad];
            bfrag[c][s] = cv.v;
        }
    }

    // xa(+b1) for this block's 16 j's: lane holds k = 32s + 8*quad + t
    const float* xaB = xa + (size_t)(b * N_ + j0 + l15) * H_ + quad * 8;
    f32x8 av[4];
    #pragma unroll
    for (int s = 0; s < 4; s++) av[s] = *(const f32x8*)(xaB + s * 32);

    float b2s[8];
    #pragma unroll
    for (int c = 0; c < 8; c++) b2s[c] = b2[16 * c + l15];

    f32x4 csum[8];
    #pragma unroll
    for (int c = 0; c < 8; c++) csum[c] = (f32x4)0.f;

    const float* xbB = xb + (size_t)(b * N_ + i0 + wid * 8) * H_ + quad * 8;

    #pragma unroll 2
    for (int r = 0; r < 8; r++) {
        const float* xr = xbB + r * H_;
        // A fragments: relu(xa[j] + xb[i]) -> bf16, packed ops
        bf16x8 afr[4];
        #pragma unroll
        for (int s = 0; s < 4; s++) {
            f32x8 u = *(const f32x8*)(xr + s * 32);
            f32x8 v = av[s] + u;
            v = __builtin_elementwise_max(v, (f32x8)0.f);
            afr[s] = __builtin_convertvector(v, bf16x8);
        }
        #pragma unroll
        for (int c = 0; c < 8; c++) {
            f32x4 acc = (f32x4)0.f;
            #pragma unroll
            for (int s = 0; s < 4; s++)
                acc = __builtin_amdgcn_mfma_f32_16x16x32_bf16(afr[s], bfrag[c][s], acc, 0, 0, 0);
            f32x4 t = acc + b2s[c];                       // +bias (splat)
            t = __builtin_elementwise_max(t, (f32x4)0.f); // relu
            csum[c] += t;                                 // row-accumulate
        }
    }

    // Reduce 4 acc-rows per lane, then quads, then waves via LDS.
    __shared__ float sred[4][H_];
    #pragma unroll
    for (int c = 0; c < 8; c++) {
        float v = (csum[c][0] + csum[c][1]) + (csum[c][2] + csum[c][3]);
        v += __shfl_xor(v, 16, 64);
        v += __shfl_xor(v, 32, 64);
        if (quad == 0) sred[wid][c * 16 + l15] = v;
    }
    __syncthreads();
    if (tid < H_) {
        float tot = sred[0][tid] + sred[1][tid] + sred[2][tid] + sred[3][tid];
        atomicAdd(&S[b * H_ + tid], tot);
    }
}

__global__ __launch_bounds__(128) void tail_kernel(
    const float* __restrict__ S, const float* __restrict__ W3,
    const float* __restrict__ b3, const float* __restrict__ V1,
    const float* __restrict__ c1, const float* __restrict__ V2,
    const float* __restrict__ c2, float* __restrict__ out)
{
    __shared__ float pool[H_], ov[H_];
    const int b = blockIdx.x, t = threadIdx.x;
    const float* Sb = S + b * H_;
    float acc = 0.f;
    #pragma unroll 8
    for (int k = 0; k < H_; k++) acc += Sb[k] * W3[k * H_ + t];
    pool[t] = acc + (float)(N_ * N_) * b3[t];
    __syncthreads();
    acc = c1[t];
    #pragma unroll 8
    for (int k = 0; k < H_; k++) acc += pool[k] * V1[k * H_ + t];
    ov[t] = acc > 0.f ? acc : 0.f;
    __syncthreads();
    if (t < OUT_) {
        acc = c2[t];
        #pragma unroll 8
        for (int k = 0; k < H_; k++) acc += ov[k] * V2[k * OUT_ + t];
        out[b * OUT_ + t] = acc;
    }
}

extern "C" void kernel_launch(void* const* d_in, const int* in_sizes, int n_in,
                              void* d_out, int out_size, void* d_ws, size_t ws_size,
                              hipStream_t stream) {
    const float* x  = (const float*)d_in[0];
    const float* W1 = (const float*)d_in[1];
    const float* b1 = (const float*)d_in[2];
    const float* W2 = (const float*)d_in[3];
    const float* b2 = (const float*)d_in[4];
    const float* W3 = (const float*)d_in[5];
    const float* b3 = (const float*)d_in[6];
    const float* V1 = (const float*)d_in[7];
    const float* c1 = (const float*)d_in[8];
    const float* V2 = (const float*)d_in[9];
    const float* c2 = (const float*)d_in[10];
    float* out = (float*)d_out;

    char* ws = (char*)d_ws;
    float*          xa  = (float*)(ws);
    float*          xb  = (float*)(ws + 524288);
    __hip_bfloat16* w2t = (__hip_bfloat16*)(ws + 1048576);
    float*          S   = (float*)(ws + 1048576 + 32768);

    prep_kernel<<<B_ * N_, 256, 0, stream>>>(x, W1, b1, W2, xa, xb, w2t, S);
    dim3 g2(N_ / 16, N_ / 32, B_);
    pair_kernel<<<g2, 256, 0, stream>>>(xa, xb, (const uint4*)w2t, b2, S);
    tail_kernel<<<B_, 128, 0, stream>>>(S, W3, b3, V1, c1, V2, c2, out);
}

// Round 5
// 131.868 us; speedup vs baseline: 1.7039x; 1.1277x over previous
//
#include <hip/hip_runtime.h>
#include <hip/hip_bf16.h>

#define B_ 2
#define N_ 512
#define D_ 64
#define H_ 128
#define OUT_ 64

using bf16x8 = __attribute__((ext_vector_type(8))) __bf16;
using f32x4  = __attribute__((ext_vector_type(4))) float;
using f32x8  = __attribute__((ext_vector_type(8))) float;

// ws layout (bytes):
//   xa_b1 : float[B*N*H]          @ 0        (524288)
//   xb    : float[B*N*H]          @ 524288   (524288)
//   w2t   : bf16 [H*H]            @ 1048576  (32768)
//   S     : float[B*H]            @ 1081344  (1024)

// One block per token (1024 blocks). Thread t: half = t>>7 selects xa/xb,
// h = t&127 the output feature.
__global__ __launch_bounds__(256) void prep_kernel(
    const float* __restrict__ x, const float* __restrict__ W1,
    const float* __restrict__ b1, const float* __restrict__ W2,
    float* __restrict__ xa, float* __restrict__ xb,
    __hip_bfloat16* __restrict__ w2t, float* __restrict__ S)
{
    const int bn  = blockIdx.x;            // b*N + n
    const int tid = threadIdx.x;
    __shared__ float xs[D_];
    if (tid < D_) xs[tid] = x[bn * D_ + tid];
    if (bn < 64) {                          // W2^T bf16: 64 blocks x 256
        int e = bn * 256 + tid;
        int k = e & (H_ - 1), n = e >> 7;
        w2t[n * H_ + k] = __float2bfloat16(W2[k * H_ + n]);
    }
    if (bn == 64) S[tid] = 0.f;             // B_*H_ = 256
    __syncthreads();

    const int h    = tid & (H_ - 1);
    const int half = tid >> 7;              // 0 -> xa (W1 rows 0..63), 1 -> xb
    const float* Wcol = W1 + half * D_ * H_ + h;
    float acc = 0.f;
    #pragma unroll
    for (int k = 0; k < D_; k++) acc += xs[k] * Wcol[k * H_];
    if (half == 0) xa[bn * H_ + h] = acc + b1[h];
    else           xb[bn * H_ + h] = acc;
}

// Block: 256 threads (4 waves). Tile: 64 i x 16 j; wave w handles i's
// [i0+16w, i0+16w+16). W2^T fragments live in registers for the whole block.
// Inner loop is s-outer/c-inner: 8 independent MFMAs per k-chunk (no acc
// dependency chains), xb chunk for iter r+1 loaded right after chunk r is
// consumed (software pipeline, single buffer).
__global__ __launch_bounds__(256, 2) void pair_kernel(
    const float* __restrict__ xa, const float* __restrict__ xb,
    const uint4* __restrict__ w2t, const float* __restrict__ b2,
    float* __restrict__ S)
{
    const int tid  = threadIdx.x;
    const int lane = tid & 63;
    const int wid  = tid >> 6;
    const int l15  = lane & 15;
    const int quad = lane >> 4;

    const int j0 = blockIdx.x * 16;
    const int i0 = blockIdx.y * 64;
    const int b  = blockIdx.z;

    // B fragments: bfrag[c][s] = W2^T[16c+l15][32s + 8*quad .. +8]
    bf16x8 bfrag[8][4];
    #pragma unroll
    for (int c = 0; c < 8; c++) {
        int row = 16 * c + l15;
        #pragma unroll
        for (int s = 0; s < 4; s++) {
            union { uint4 u; bf16x8 v; } cv;
            cv.u = w2t[row * 16 + s * 4 + quad];
            bfrag[c][s] = cv.v;
        }
    }

    // xa(+b1) for this block's 16 j's: lane holds k = 32s + 8*quad + t
    const float* xaB = xa + (size_t)(b * N_ + j0 + l15) * H_ + quad * 8;
    f32x8 av[4];
    #pragma unroll
    for (int s = 0; s < 4; s++) av[s] = *(const f32x8*)(xaB + s * 32);

    float b2s[8];
    #pragma unroll
    for (int c = 0; c < 8; c++) b2s[c] = b2[16 * c + l15];

    float csum[8];
    #pragma unroll
    for (int c = 0; c < 8; c++) csum[c] = 0.f;

    const f32x4 czero = (f32x4)0.f;
    const float* xbB = xb + (size_t)(b * N_ + i0 + wid * 16) * H_ + quad * 8;

    // preload iter 0's xb chunks
    f32x8 cur[4];
    #pragma unroll
    for (int s = 0; s < 4; s++) cur[s] = *(const f32x8*)(xbB + s * 32);

    #pragma unroll 1
    for (int r = 0; r < 16; r++) {
        const float* nxtp = xbB + ((r + 1) & 15) * H_;  // wrap: last iter reloads row 0 (harmless)
        f32x4 acc[8];
        #pragma unroll
        for (int s = 0; s < 4; s++) {
            // A fragment: relu(xa[j] + xb[i]) -> bf16 (packed)
            f32x8 v = av[s] + cur[s];
            v = __builtin_elementwise_max(v, (f32x8)0.f);
            bf16x8 a = __builtin_convertvector(v, bf16x8);
            cur[s] = *(const f32x8*)(nxtp + s * 32);    // prefetch next iter's chunk
            if (s == 0) {
                #pragma unroll
                for (int c = 0; c < 8; c++)
                    acc[c] = __builtin_amdgcn_mfma_f32_16x16x32_bf16(a, bfrag[c][0], czero, 0, 0, 0);
            } else {
                #pragma unroll
                for (int c = 0; c < 8; c++)
                    acc[c] = __builtin_amdgcn_mfma_f32_16x16x32_bf16(a, bfrag[c][s], acc[c], 0, 0, 0);
            }
        }
        // epilogue: relu(acc + b2), fold 4 rows into scalar column sums
        #pragma unroll
        for (int c = 0; c < 8; c++) {
            f32x4 t = acc[c] + b2s[c];
            t = __builtin_elementwise_max(t, czero);
            csum[c] += (t[0] + t[1]) + (t[2] + t[3]);
        }
    }

    // cross-quad reduction, then cross-wave via LDS, one atomic per column
    __shared__ float sred[4][H_];
    #pragma unroll
    for (int c = 0; c < 8; c++) {
        float v = csum[c];
        v += __shfl_xor(v, 16, 64);
        v += __shfl_xor(v, 32, 64);
        if (quad == 0) sred[wid][c * 16 + l15] = v;
    }
    __syncthreads();
    if (tid < H_) {
        float tot = sred[0][tid] + sred[1][tid] + sred[2][tid] + sred[3][tid];
        atomicAdd(&S[b * H_ + tid], tot);
    }
}

__global__ __launch_bounds__(128) void tail_kernel(
    const float* __restrict__ S, const float* __restrict__ W3,
    const float* __restrict__ b3, const float* __restrict__ V1,
    const float* __restrict__ c1, const float* __restrict__ V2,
    const float* __restrict__ c2, float* __restrict__ out)
{
    __shared__ float pool[H_], ov[H_];
    const int b = blockIdx.x, t = threadIdx.x;
    const float* Sb = S + b * H_;
    float acc = 0.f;
    #pragma unroll 8
    for (int k = 0; k < H_; k++) acc += Sb[k] * W3[k * H_ + t];
    pool[t] = acc + (float)(N_ * N_) * b3[t];
    __syncthreads();
    acc = c1[t];
    #pragma unroll 8
    for (int k = 0; k < H_; k++) acc += pool[k] * V1[k * H_ + t];
    ov[t] = acc > 0.f ? acc : 0.f;
    __syncthreads();
    if (t < OUT_) {
        acc = c2[t];
        #pragma unroll 8
        for (int k = 0; k < H_; k++) acc += ov[k] * V2[k * OUT_ + t];
        out[b * OUT_ + t] = acc;
    }
}

extern "C" void kernel_launch(void* const* d_in, const int* in_sizes, int n_in,
                              void* d_out, int out_size, void* d_ws, size_t ws_size,
                              hipStream_t stream) {
    const float* x  = (const float*)d_in[0];
    const float* W1 = (const float*)d_in[1];
    const float* b1 = (const float*)d_in[2];
    const float* W2 = (const float*)d_in[3];
    const float* b2 = (const float*)d_in[4];
    const float* W3 = (const float*)d_in[5];
    const float* b3 = (const float*)d_in[6];
    const float* V1 = (const float*)d_in[7];
    const float* c1 = (const float*)d_in[8];
    const float* V2 = (const float*)d_in[9];
    const float* c2 = (const float*)d_in[10];
    float* out = (float*)d_out;

    char* ws = (char*)d_ws;
    float*          xa  = (float*)(ws);
    float*          xb  = (float*)(ws + 524288);
    __hip_bfloat16* w2t = (__hip_bfloat16*)(ws + 1048576);
    float*          S   = (float*)(ws + 1048576 + 32768);

    prep_kernel<<<B_ * N_, 256, 0, stream>>>(x, W1, b1, W2, xa, xb, w2t, S);
    dim3 g2(N_ / 16, N_ / 64, B_);
    pair_kernel<<<g2, 256, 0, stream>>>(xa, xb, (const uint4*)w2t, b2, S);
    tail_kernel<<<B_, 128, 0, stream>>>(S, W3, b3, V1, c1, V2, c2, out);
}

// Round 6
// 125.732 us; speedup vs baseline: 1.7870x; 1.0488x over previous
//
#include <hip/hip_runtime.h>
#include <hip/hip_bf16.h>

#define B_ 2
#define N_ 512
#define D_ 64
#define H_ 128
#define OUT_ 64

using bf16x8 = __attribute__((ext_vector_type(8))) __bf16;
using f32x4  = __attribute__((ext_vector_type(4))) float;
using f32x8  = __attribute__((ext_vector_type(8))) float;

// ws layout (bytes):
//   xa_b1 : float[B*N*H]          @ 0        (524288)
//   xb    : float[B*N*H]          @ 524288   (524288)
//   w2t   : bf16 [H*H]            @ 1048576  (32768)
//   S     : float[B*H]            @ 1081344  (1024)

__global__ __launch_bounds__(256) void prep_kernel(
    const float* __restrict__ x, const float* __restrict__ W1,
    const float* __restrict__ b1, const float* __restrict__ W2,
    float* __restrict__ xa, float* __restrict__ xb,
    __hip_bfloat16* __restrict__ w2t, float* __restrict__ S)
{
    const int bn  = blockIdx.x;            // b*N + n
    const int tid = threadIdx.x;
    __shared__ float xs[D_];
    if (tid < D_) xs[tid] = x[bn * D_ + tid];
    if (bn < 64) {                          // W2^T bf16: 64 blocks x 256
        int e = bn * 256 + tid;
        int k = e & (H_ - 1), n = e >> 7;
        w2t[n * H_ + k] = __float2bfloat16(W2[k * H_ + n]);
    }
    if (bn == 64) S[tid] = 0.f;             // B_*H_ = 256
    __syncthreads();

    const int h    = tid & (H_ - 1);
    const int half = tid >> 7;              // 0 -> xa (W1 rows 0..63), 1 -> xb
    const float* Wcol = W1 + half * D_ * H_ + h;
    float acc = 0.f;
    #pragma unroll
    for (int k = 0; k < D_; k++) acc += xs[k] * Wcol[k * H_];
    if (half == 0) xa[bn * H_ + h] = acc + b1[h];
    else           xb[bn * H_ + h] = acc;
}

// Block: 256 threads (4 waves). Tile: 64 i x 16 j; wave w handles i's
// [i0+16w, i0+16w+16). The block's xa/xb tiles are bulk-staged into LDS
// with coalesced uint4 loads (one latency hit, all outstanding), so the
// MFMA main loop touches no global memory. W2^T fragments in registers.
__global__ __launch_bounds__(256, 2) void pair_kernel(
    const float* __restrict__ xa, const float* __restrict__ xb,
    const uint4* __restrict__ w2t, const float* __restrict__ b2,
    float* __restrict__ S)
{
    __shared__ float xbs[64 * H_];     // 32 KB
    __shared__ float xas[16 * H_];     // 8 KB
    __shared__ float sred[4][H_];      // 2 KB

    const int tid  = threadIdx.x;
    const int lane = tid & 63;
    const int wid  = tid >> 6;
    const int l15  = lane & 15;
    const int quad = lane >> 4;

    const int j0 = blockIdx.x * 16;
    const int i0 = blockIdx.y * 64;
    const int b  = blockIdx.z;

    // ---- bulk stage: xb tile (8 rounds) + xa tile (2 rounds), coalesced ----
    {
        const uint4* sb = (const uint4*)(xb + (size_t)(b * N_ + i0) * H_);
        uint4* db = (uint4*)xbs;
        #pragma unroll
        for (int rnd = 0; rnd < 8; rnd++) db[rnd * 256 + tid] = sb[rnd * 256 + tid];
        const uint4* sa = (const uint4*)(xa + (size_t)(b * N_ + j0) * H_);
        uint4* da = (uint4*)xas;
        #pragma unroll
        for (int rnd = 0; rnd < 2; rnd++) da[rnd * 256 + tid] = sa[rnd * 256 + tid];
    }

    // B fragments (global, L2-hot, overlaps staging): bfrag[c][s] =
    // W2^T[16c+l15][32s + 8*quad .. +8]
    bf16x8 bfrag[8][4];
    #pragma unroll
    for (int c = 0; c < 8; c++) {
        int row = 16 * c + l15;
        #pragma unroll
        for (int s = 0; s < 4; s++) {
            union { uint4 u; bf16x8 v; } cv;
            cv.u = w2t[row * 16 + s * 4 + quad];
            bfrag[c][s] = cv.v;
        }
    }
    float b2s[8];
    #pragma unroll
    for (int c = 0; c < 8; c++) b2s[c] = b2[16 * c + l15];

    __syncthreads();

    // xa(+b1) fragments from LDS: lane holds k = 32s + 8*quad + t
    f32x8 av[4];
    #pragma unroll
    for (int s = 0; s < 4; s++)
        av[s] = *(const f32x8*)(xas + l15 * H_ + quad * 8 + s * 32);

    f32x4 csum[8];
    #pragma unroll
    for (int c = 0; c < 8; c++) csum[c] = (f32x4)0.f;

    const f32x4 czero = (f32x4)0.f;
    const float* xrow = xbs + (wid * 16) * H_ + quad * 8;

    #pragma unroll 1
    for (int r = 0; r < 16; r++) {
        const float* xr = xrow + r * H_;
        f32x4 acc[8];
        #pragma unroll
        for (int s = 0; s < 4; s++) {
            f32x8 u = *(const f32x8*)(xr + s * 32);       // LDS broadcast read
            f32x8 v = av[s] + u;
            v = __builtin_elementwise_max(v, (f32x8)0.f);
            bf16x8 a = __builtin_convertvector(v, bf16x8);
            if (s == 0) {
                #pragma unroll
                for (int c = 0; c < 8; c++)
                    acc[c] = __builtin_amdgcn_mfma_f32_16x16x32_bf16(a, bfrag[c][0], czero, 0, 0, 0);
            } else {
                #pragma unroll
                for (int c = 0; c < 8; c++)
                    acc[c] = __builtin_amdgcn_mfma_f32_16x16x32_bf16(a, bfrag[c][s], acc[c], 0, 0, 0);
            }
        }
        // epilogue: relu(acc + b2), vector row-accumulate
        #pragma unroll
        for (int c = 0; c < 8; c++) {
            f32x4 t = acc[c] + b2s[c];
            t = __builtin_elementwise_max(t, czero);
            csum[c] += t;
        }
    }

    // fold 4 acc-rows, cross-quad, cross-wave via LDS, one atomic per column
    #pragma unroll
    for (int c = 0; c < 8; c++) {
        float v = (csum[c][0] + csum[c][1]) + (csum[c][2] + csum[c][3]);
        v += __shfl_xor(v, 16, 64);
        v += __shfl_xor(v, 32, 64);
        if (quad == 0) sred[wid][c * 16 + l15] = v;
    }
    __syncthreads();
    if (tid < H_) {
        float tot = sred[0][tid] + sred[1][tid] + sred[2][tid] + sred[3][tid];
        atomicAdd(&S[b * H_ + tid], tot);
    }
}

__global__ __launch_bounds__(128) void tail_kernel(
    const float* __restrict__ S, const float* __restrict__ W3,
    const float* __restrict__ b3, const float* __restrict__ V1,
    const float* __restrict__ c1, const float* __restrict__ V2,
    const float* __restrict__ c2, float* __restrict__ out)
{
    __shared__ float pool[H_], ov[H_];
    const int b = blockIdx.x, t = threadIdx.x;
    const float* Sb = S + b * H_;
    float acc = 0.f;
    #pragma unroll 8
    for (int k = 0; k < H_; k++) acc += Sb[k] * W3[k * H_ + t];
    pool[t] = acc + (float)(N_ * N_) * b3[t];
    __syncthreads();
    acc = c1[t];
    #pragma unroll 8
    for (int k = 0; k < H_; k++) acc += pool[k] * V1[k * H_ + t];
    ov[t] = acc > 0.f ? acc : 0.f;
    __syncthreads();
    if (t < OUT_) {
        acc = c2[t];
        #pragma unroll 8
        for (int k = 0; k < H_; k++) acc += ov[k] * V2[k * OUT_ + t];
        out[b * OUT_ + t] = acc;
    }
}

extern "C" void kernel_launch(void* const* d_in, const int* in_sizes, int n_in,
                              void* d_out, int out_size, void* d_ws, size_t ws_size,
                              hipStream_t stream) {
    const float* x  = (const float*)d_in[0];
    const float* W1 = (const float*)d_in[1];
    const float* b1 = (const float*)d_in[2];
    const float* W2 = (const float*)d_in[3];
    const float* b2 = (const float*)d_in[4];
    const float* W3 = (const float*)d_in[5];
    const float* b3 = (const float*)d_in[6];
    const float* V1 = (const float*)d_in[7];
    const float* c1 = (const float*)d_in[8];
    const float* V2 = (const float*)d_in[9];
    const float* c2 = (const float*)d_in[10];
    float* out = (float*)d_out;

    char* ws = (char*)d_ws;
    float*          xa  = (float*)(ws);
    float*          xb  = (float*)(ws + 524288);
    __hip_bfloat16* w2t = (__hip_bfloat16*)(ws + 1048576);
    float*          S   = (float*)(ws + 1048576 + 32768);

    prep_kernel<<<B_ * N_, 256, 0, stream>>>(x, W1, b1, W2, xa, xb, w2t, S);
    dim3 g2(N_ / 16, N_ / 64, B_);
    pair_kernel<<<g2, 256, 0, stream>>>(xa, xb, (const uint4*)w2t, b2, S);
    tail_kernel<<<B_, 128, 0, stream>>>(S, W3, b3, V1, c1, V2, c2, out);
}